// Round 1
// baseline (198.797 us; speedup 1.0000x reference)
//
#include <hip/hip_runtime.h>
#include <stdint.h>

typedef __attribute__((ext_vector_type(8))) short short8;
typedef __attribute__((ext_vector_type(4))) float f32x4;
typedef __attribute__((ext_vector_type(4))) unsigned short ushort4v;

static __device__ __forceinline__ unsigned short f2b(float f) {
  union { float f; unsigned int u; } v; v.f = f;
  unsigned int r = v.u + 0x7FFFu + ((v.u >> 16) & 1u);
  return (unsigned short)(r >> 16);
}

static __device__ __forceinline__ void gload16(const void* g, void* l) {
  __builtin_amdgcn_global_load_lds(
      (const __attribute__((address_space(1))) unsigned int*)g,
      (__attribute__((address_space(3))) unsigned int*)l, 16, 0, 0);
}

// ---------------- prep kernels ----------------

__global__ __launch_bounds__(256) void cast_x_kernel(const float* __restrict__ x,
                                                     unsigned short* __restrict__ xb) {
  int i = (blockIdx.x * 256 + threadIdx.x) * 4;
  float4 v = *(const float4*)(x + i);
  ushort4v o = { f2b(v.x), f2b(v.y), f2b(v.z), f2b(v.w) };
  *(ushort4v*)(xb + i) = o;
}

__global__ __launch_bounds__(256) void transpose_cast_kernel(
    const float* __restrict__ wq, const float* __restrict__ wk,
    const float* __restrict__ wv, const float* __restrict__ wo,
    unsigned short* __restrict__ wT) {
  const int z = blockIdx.z;
  const float* src = (z == 0) ? wq : (z == 1) ? wk : (z == 2) ? wv : wo;
  unsigned short* dst = wT + (size_t)z * 1048576;
  __shared__ float t[32][33];
  const int tid = threadIdx.x;
  const int tx = tid & 31, ty = tid >> 5;
  const int n0 = blockIdx.x * 32, k0 = blockIdx.y * 32;
#pragma unroll
  for (int i = 0; i < 4; ++i) {
    int r = ty + i * 8;
    t[r][tx] = src[(size_t)(k0 + r) * 1024 + n0 + tx];
  }
  __syncthreads();
#pragma unroll
  for (int i = 0; i < 4; ++i) {
    int r = ty + i * 8;
    dst[(size_t)(n0 + r) * 1024 + k0 + tx] = f2b(t[tx][r]);
  }
}

__global__ __launch_bounds__(256) void rope_tab_kernel(float* __restrict__ ct,
                                                       float* __restrict__ st) {
  int i = blockIdx.x * 256 + threadIdx.x;  // 2048*32 entries
  int s = i >> 5, p = i & 31;
  float ang = (float)s * powf(10000.0f, -(float)(2 * p) / 64.0f);
  ct[i] = cosf(ang);
  st[i] = sinf(ang);
}

// ---------------- GEMM (A: MxK row-major bf16, Bt: NxK row-major bf16) ----------------
// mode 0: Q epilogue (RoPE, write (h,b,s,d)); mode 1: K epilogue (same);
// mode 2: V epilogue (write transposed (h,b,d,s)); mode 3: fp32 row-major out.

__global__ __launch_bounds__(256) void gemm_kernel(
    const unsigned short* __restrict__ A, const unsigned short* __restrict__ WT,
    unsigned short* __restrict__ Qb, unsigned short* __restrict__ Kb,
    unsigned short* __restrict__ VTb, float* __restrict__ Fout,
    const float* __restrict__ ctab, const float* __restrict__ stab, int finalMode) {
  __shared__ unsigned short As[128 * 32];
  __shared__ unsigned short Bs[128 * 32];
  const int tid = threadIdx.x;
  const int w = tid >> 6, lane = tid & 63;
  const int m0 = blockIdx.x * 128, n0 = blockIdx.y * 128;
  int mode;
  const unsigned short* Bt;
  if (finalMode) { mode = 3; Bt = WT; }
  else { mode = blockIdx.z; Bt = WT + (size_t)mode * 1048576; }
  const int wr = w >> 1, wc = w & 1;
  const int srow = lane >> 2, scol = lane & 3;
  f32x4 acc[4][4] = {};
  for (int k0 = 0; k0 < 1024; k0 += 32) {
#pragma unroll
    for (int c = 0; c < 2; ++c) {
      int chunk = w * 2 + c;
      gload16(A + (size_t)(m0 + chunk * 16 + srow) * 1024 + k0 + scol * 8,
              (char*)As + chunk * 1024);
      gload16(Bt + (size_t)(n0 + chunk * 16 + srow) * 1024 + k0 + scol * 8,
              (char*)Bs + chunk * 1024);
    }
    __syncthreads();
    short8 af[4], bf[4];
#pragma unroll
    for (int i = 0; i < 4; ++i) {
      af[i] = *(const short8*)((const char*)As +
              ((wr * 64 + i * 16 + (lane & 15)) * 64 + (lane >> 4) * 16));
      bf[i] = *(const short8*)((const char*)Bs +
              ((wc * 64 + i * 16 + (lane & 15)) * 64 + (lane >> 4) * 16));
    }
#pragma unroll
    for (int i = 0; i < 4; ++i)
#pragma unroll
      for (int j = 0; j < 4; ++j)
        acc[i][j] = __builtin_amdgcn_mfma_f32_16x16x32_bf16(af[i], bf[j], acc[i][j], 0, 0, 0);
    __syncthreads();
  }

  if (mode < 2) {
    unsigned short* dst = mode ? Kb : Qb;
#pragma unroll
    for (int i = 0; i < 4; ++i) {
#pragma unroll
      for (int j = 0; j < 4; ++j) {
        int n = n0 + wc * 64 + j * 16 + (lane & 15);
        int h = n >> 6, d = n & 63;
        int pairIdx = d >> 1;
        bool even = (n & 1) == 0;
#pragma unroll
        for (int r = 0; r < 4; ++r) {
          int m = m0 + wr * 64 + i * 16 + (lane >> 4) * 4 + r;
          int b = m >> 11, s = m & 2047;
          float v = acc[i][j][r];
          float pv = __shfl_xor(v, 1);
          float c = ctab[s * 32 + pairIdx], sn = stab[s * 32 + pairIdx];
          float ov = even ? (v * c - pv * sn) : (pv * sn + v * c);
          dst[(size_t)((h * 2 + b) * 2048 + s) * 64 + d] = f2b(ov);
        }
      }
    }
  } else if (mode == 2) {
#pragma unroll
    for (int i = 0; i < 4; ++i) {
#pragma unroll
      for (int j = 0; j < 4; ++j) {
        int n = n0 + wc * 64 + j * 16 + (lane & 15);
        int h = n >> 6, d = n & 63;
        int mBase = m0 + wr * 64 + i * 16 + (lane >> 4) * 4;
        int b = mBase >> 11, s = mBase & 2047;
        ushort4v pk = { f2b(acc[i][j][0]), f2b(acc[i][j][1]),
                        f2b(acc[i][j][2]), f2b(acc[i][j][3]) };
        *(ushort4v*)(VTb + (size_t)((h * 2 + b) * 64 + d) * 2048 + s) = pk;
      }
    }
  } else {
#pragma unroll
    for (int i = 0; i < 4; ++i)
#pragma unroll
      for (int j = 0; j < 4; ++j) {
        int n = n0 + wc * 64 + j * 16 + (lane & 15);
#pragma unroll
        for (int r = 0; r < 4; ++r) {
          int m = m0 + wr * 64 + i * 16 + (lane >> 4) * 4 + r;
          Fout[(size_t)m * 1024 + n] = acc[i][j][r];
        }
      }
  }
}

// ---------------- causal flash attention ----------------

__global__ __launch_bounds__(256) void attn_kernel(
    const unsigned short* __restrict__ Qb, const unsigned short* __restrict__ Kb,
    const unsigned short* __restrict__ VTb, unsigned short* __restrict__ Ob) {
  __shared__ unsigned short Ks[64 * 64];
  __shared__ unsigned short Vs[64 * 64];
  __shared__ unsigned short Ps[4 * 16 * 64];
  const int tid = threadIdx.x, w = tid >> 6, lane = tid & 63;
  const int qt = blockIdx.x, hb = blockIdx.y;
  const int h = hb >> 1, b = hb & 1;
  const int qb = qt * 64;
  const unsigned short* Qhb = Qb + (size_t)hb * 2048 * 64;
  const unsigned short* Khb = Kb + (size_t)hb * 2048 * 64;
  const unsigned short* Vhb = VTb + (size_t)hb * 64 * 2048;

  short8 aq[2];
  {
    int row = qb + w * 16 + (lane & 15);
#pragma unroll
    for (int ks = 0; ks < 2; ++ks)
      aq[ks] = *(const short8*)(Qhb + (size_t)row * 64 + ks * 32 + (lane >> 4) * 8);
  }
  float mrow[4], lsum[4];
#pragma unroll
  for (int r = 0; r < 4; ++r) { mrow[r] = -__builtin_inff(); lsum[r] = 0.f; }
  f32x4 oacc[4] = {};

  for (int kt = 0; kt <= qt; ++kt) {
    const int kk0 = kt * 64;
#pragma unroll
    for (int it = 0; it < 2; ++it) {
      int idx = tid + it * 256;       // 512 chunks of 16B
      int row = idx >> 3, c16 = idx & 7;
      int so = row * 128 + ((c16 * 16) ^ ((row & 7) << 4));
      *(short8*)((char*)Ks + so) = *(const short8*)(Khb + (size_t)(kk0 + row) * 64 + c16 * 8);
      *(short8*)((char*)Vs + so) = *(const short8*)(Vhb + (size_t)row * 2048 + kk0 + c16 * 8);
    }
    __syncthreads();

    f32x4 sacc[4] = {};
#pragma unroll
    for (int ct = 0; ct < 4; ++ct) {
      int row = ct * 16 + (lane & 15);
#pragma unroll
      for (int ks = 0; ks < 2; ++ks) {
        short8 bk = *(const short8*)((const char*)Ks + row * 128 +
                    ((ks * 64 + (lane >> 4) * 16) ^ ((row & 7) << 4)));
        sacc[ct] = __builtin_amdgcn_mfma_f32_16x16x32_bf16(aq[ks], bk, sacc[ct], 0, 0, 0);
      }
    }

    const bool diag = (kt == qt);
#pragma unroll
    for (int r = 0; r < 4; ++r) {
      int qrow = w * 16 + (lane >> 4) * 4 + r;  // block-local q row
      float mx = -__builtin_inff();
#pragma unroll
      for (int ct = 0; ct < 4; ++ct) {
        float v = sacc[ct][r] * 0.125f;
        if (diag && (ct * 16 + (lane & 15)) > qrow) v = -__builtin_inff();
        sacc[ct][r] = v;
        mx = fmaxf(mx, v);
      }
#pragma unroll
      for (int dd = 1; dd < 16; dd <<= 1) mx = fmaxf(mx, __shfl_xor(mx, dd));
      float nm = fmaxf(mrow[r], mx);
      float al = __expf(mrow[r] - nm);
      mrow[r] = nm;
      float ps = 0.f;
#pragma unroll
      for (int ct = 0; ct < 4; ++ct) {
        float p = __expf(sacc[ct][r] - nm);
        sacc[ct][r] = p;
        ps += p;
      }
#pragma unroll
      for (int dd = 1; dd < 16; dd <<= 1) ps += __shfl_xor(ps, dd);
      lsum[r] = lsum[r] * al + ps;
#pragma unroll
      for (int ct = 0; ct < 4; ++ct) oacc[ct][r] *= al;
    }

    // wave-private P -> LDS (swizzled), then read back as A-fragments
#pragma unroll
    for (int ct = 0; ct < 4; ++ct)
#pragma unroll
      for (int r = 0; r < 4; ++r) {
        int row = (lane >> 4) * 4 + r;
        int cb = 2 * (ct * 16 + (lane & 15));
        *(unsigned short*)((char*)Ps + w * 2048 + row * 128 + (cb ^ ((row & 7) << 4))) =
            f2b(sacc[ct][r]);
      }
    __builtin_amdgcn_wave_barrier();
    short8 pa[2];
    {
      int row = lane & 15;
#pragma unroll
      for (int ks = 0; ks < 2; ++ks)
        pa[ks] = *(const short8*)((const char*)Ps + w * 2048 + row * 128 +
                 ((ks * 64 + (lane >> 4) * 16) ^ ((row & 7) << 4)));
    }
#pragma unroll
    for (int ct = 0; ct < 4; ++ct) {
      int row = ct * 16 + (lane & 15);
#pragma unroll
      for (int ks = 0; ks < 2; ++ks) {
        short8 bv = *(const short8*)((const char*)Vs + row * 128 +
                    ((ks * 64 + (lane >> 4) * 16) ^ ((row & 7) << 4)));
        oacc[ct] = __builtin_amdgcn_mfma_f32_16x16x32_bf16(pa[ks], bv, oacc[ct], 0, 0, 0);
      }
    }
    __syncthreads();
  }

#pragma unroll
  for (int ct = 0; ct < 4; ++ct) {
    int col = h * 64 + ct * 16 + (lane & 15);
#pragma unroll
    for (int r = 0; r < 4; ++r) {
      int s = qb + w * 16 + (lane >> 4) * 4 + r;
      float v = oacc[ct][r] / lsum[r];
      Ob[(size_t)(b * 2048 + s) * 1024 + col] = f2b(v);
    }
  }
}

// ---------------- launch ----------------

extern "C" void kernel_launch(void* const* d_in, const int* in_sizes, int n_in,
                              void* d_out, int out_size, void* d_ws, size_t ws_size,
                              hipStream_t stream) {
  const float* x  = (const float*)d_in[0];
  const float* wq = (const float*)d_in[1];
  const float* wk = (const float*)d_in[2];
  const float* wv = (const float*)d_in[3];
  const float* wo = (const float*)d_in[4];
  float* out = (float*)d_out;

  char* ws = (char*)d_ws;
  const size_t SZ = 8388608;  // 8 MiB
  unsigned short* xb  = (unsigned short*)(ws);
  unsigned short* wT  = (unsigned short*)(ws + SZ);       // 4 x 2MiB (q,k,v,o)
  unsigned short* Qb  = (unsigned short*)(ws + 2 * SZ);
  unsigned short* Kb  = (unsigned short*)(ws + 3 * SZ);
  unsigned short* VTb = (unsigned short*)(ws + 4 * SZ);
  unsigned short* Ob  = (unsigned short*)(ws + 5 * SZ);
  float* ctab = (float*)(ws + 6 * SZ);
  float* stab = (float*)(ws + 6 * SZ + 262144);
  if (ws_size < 6 * SZ + 2 * 262144) return;  // ws too small: fail loudly (zeros)

  cast_x_kernel<<<4096, 256, 0, stream>>>(x, xb);
  transpose_cast_kernel<<<dim3(32, 32, 4), 256, 0, stream>>>(wq, wk, wv, wo, wT);
  rope_tab_kernel<<<256, 256, 0, stream>>>(ctab, stab);
  gemm_kernel<<<dim3(32, 8, 3), 256, 0, stream>>>(xb, wT, Qb, Kb, VTb, nullptr, ctab, stab, 0);
  attn_kernel<<<dim3(32, 32), 256, 0, stream>>>(Qb, Kb, VTb, Ob);
  gemm_kernel<<<dim3(32, 8, 1), 256, 0, stream>>>(Ob, wT + 3 * 1048576, Qb, Kb, VTb, out,
                                                  ctab, stab, 1);
}

// Round 2
// 151.116 us; speedup vs baseline: 1.3155x; 1.3155x over previous
//
#include <hip/hip_runtime.h>
#include <stdint.h>

typedef __attribute__((ext_vector_type(8))) short short8;
typedef __attribute__((ext_vector_type(4))) float f32x4;
typedef __attribute__((ext_vector_type(4))) unsigned short ushort4v;

static __device__ __forceinline__ unsigned short f2b(float f) {
  union { float f; unsigned int u; } v; v.f = f;
  unsigned int r = v.u + 0x7FFFu + ((v.u >> 16) & 1u);
  return (unsigned short)(r >> 16);
}

static __device__ __forceinline__ float exp2fast(float x) {
#if __has_builtin(__builtin_amdgcn_exp2f)
  return __builtin_amdgcn_exp2f(x);
#else
  return exp2f(x);
#endif
}

static __device__ __forceinline__ void gload16(const void* g, void* l) {
  __builtin_amdgcn_global_load_lds(
      (const __attribute__((address_space(1))) unsigned int*)g,
      (__attribute__((address_space(3))) unsigned int*)l, 16, 0, 0);
}

// ---------------- prep kernels ----------------

__global__ __launch_bounds__(256) void cast_x_kernel(const float* __restrict__ x,
                                                     unsigned short* __restrict__ xb) {
  int i = (blockIdx.x * 256 + threadIdx.x) * 4;
  float4 v = *(const float4*)(x + i);
  ushort4v o = { f2b(v.x), f2b(v.y), f2b(v.z), f2b(v.w) };
  *(ushort4v*)(xb + i) = o;
}

__global__ __launch_bounds__(256) void transpose_cast_kernel(
    const float* __restrict__ wq, const float* __restrict__ wk,
    const float* __restrict__ wv, const float* __restrict__ wo,
    unsigned short* __restrict__ wT) {
  const int z = blockIdx.z;
  const float* src = (z == 0) ? wq : (z == 1) ? wk : (z == 2) ? wv : wo;
  unsigned short* dst = wT + (size_t)z * 1048576;
  __shared__ float t[32][33];
  const int tid = threadIdx.x;
  const int tx = tid & 31, ty = tid >> 5;
  const int n0 = blockIdx.x * 32, k0 = blockIdx.y * 32;
#pragma unroll
  for (int i = 0; i < 4; ++i) {
    int r = ty + i * 8;
    t[r][tx] = src[(size_t)(k0 + r) * 1024 + n0 + tx];
  }
  __syncthreads();
#pragma unroll
  for (int i = 0; i < 4; ++i) {
    int r = ty + i * 8;
    dst[(size_t)(n0 + r) * 1024 + k0 + tx] = f2b(t[tx][r]);
  }
}

__global__ __launch_bounds__(256) void rope_tab_kernel(float* __restrict__ ct,
                                                       float* __restrict__ st) {
  int i = blockIdx.x * 256 + threadIdx.x;  // 2048*32 entries
  int s = i >> 5, p = i & 31;
  float ang = (float)s * powf(10000.0f, -(float)(2 * p) / 64.0f);
  ct[i] = cosf(ang);
  st[i] = sinf(ang);
}

// ---------------- GEMM (A: MxK row-major bf16, Bt: NxK row-major bf16) ----------------
// mode 0: Q epilogue (RoPE + fold 0.125*log2e, write (h,b,s,d)); mode 1: K epilogue;
// mode 2: V epilogue (write transposed (h,b,d,s)); mode 3: fp32 row-major out.

__global__ __launch_bounds__(256) void gemm_kernel(
    const unsigned short* __restrict__ A, const unsigned short* __restrict__ WT,
    unsigned short* __restrict__ Qb, unsigned short* __restrict__ Kb,
    unsigned short* __restrict__ VTb, float* __restrict__ Fout,
    const float* __restrict__ ctab, const float* __restrict__ stab, int finalMode) {
  __shared__ unsigned short As[128 * 32];
  __shared__ unsigned short Bs[128 * 32];
  const int tid = threadIdx.x;
  const int w = tid >> 6, lane = tid & 63;
  const int m0 = blockIdx.x * 128, n0 = blockIdx.y * 128;
  int mode;
  const unsigned short* Bt;
  if (finalMode) { mode = 3; Bt = WT; }
  else { mode = blockIdx.z; Bt = WT + (size_t)mode * 1048576; }
  const int wr = w >> 1, wc = w & 1;
  const int srow = lane >> 2, scol = lane & 3;
  f32x4 acc[4][4] = {};
  for (int k0 = 0; k0 < 1024; k0 += 32) {
#pragma unroll
    for (int c = 0; c < 2; ++c) {
      int chunk = w * 2 + c;
      gload16(A + (size_t)(m0 + chunk * 16 + srow) * 1024 + k0 + scol * 8,
              (char*)As + chunk * 1024);
      gload16(Bt + (size_t)(n0 + chunk * 16 + srow) * 1024 + k0 + scol * 8,
              (char*)Bs + chunk * 1024);
    }
    __syncthreads();
    short8 af[4], bf[4];
#pragma unroll
    for (int i = 0; i < 4; ++i) {
      af[i] = *(const short8*)((const char*)As +
              ((wr * 64 + i * 16 + (lane & 15)) * 64 + (lane >> 4) * 16));
      bf[i] = *(const short8*)((const char*)Bs +
              ((wc * 64 + i * 16 + (lane & 15)) * 64 + (lane >> 4) * 16));
    }
#pragma unroll
    for (int i = 0; i < 4; ++i)
#pragma unroll
      for (int j = 0; j < 4; ++j)
        acc[i][j] = __builtin_amdgcn_mfma_f32_16x16x32_bf16(af[i], bf[j], acc[i][j], 0, 0, 0);
    __syncthreads();
  }

  if (mode < 2) {
    unsigned short* dst = mode ? Kb : Qb;
    const float qscale = mode ? 1.0f : 0.125f * 1.44269504088896f;
#pragma unroll
    for (int i = 0; i < 4; ++i) {
#pragma unroll
      for (int j = 0; j < 4; ++j) {
        int n = n0 + wc * 64 + j * 16 + (lane & 15);
        int h = n >> 6, d = n & 63;
        int pairIdx = d >> 1;
        bool even = (n & 1) == 0;
#pragma unroll
        for (int r = 0; r < 4; ++r) {
          int m = m0 + wr * 64 + i * 16 + (lane >> 4) * 4 + r;
          int b = m >> 11, s = m & 2047;
          float v = acc[i][j][r];
          float pv = __shfl_xor(v, 1);
          float c = ctab[s * 32 + pairIdx], sn = stab[s * 32 + pairIdx];
          float ov = (even ? (v * c - pv * sn) : (pv * sn + v * c)) * qscale;
          dst[(size_t)((h * 2 + b) * 2048 + s) * 64 + d] = f2b(ov);
        }
      }
    }
  } else if (mode == 2) {
#pragma unroll
    for (int i = 0; i < 4; ++i) {
#pragma unroll
      for (int j = 0; j < 4; ++j) {
        int n = n0 + wc * 64 + j * 16 + (lane & 15);
        int h = n >> 6, d = n & 63;
        int mBase = m0 + wr * 64 + i * 16 + (lane >> 4) * 4;
        int b = mBase >> 11, s = mBase & 2047;
        ushort4v pk = { f2b(acc[i][j][0]), f2b(acc[i][j][1]),
                        f2b(acc[i][j][2]), f2b(acc[i][j][3]) };
        *(ushort4v*)(VTb + (size_t)((h * 2 + b) * 64 + d) * 2048 + s) = pk;
      }
    }
  } else {
#pragma unroll
    for (int i = 0; i < 4; ++i)
#pragma unroll
      for (int j = 0; j < 4; ++j) {
        int n = n0 + wc * 64 + j * 16 + (lane & 15);
#pragma unroll
        for (int r = 0; r < 4; ++r) {
          int m = m0 + wr * 64 + i * 16 + (lane >> 4) * 4 + r;
          Fout[(size_t)m * 1024 + n] = acc[i][j][r];
        }
      }
  }
}

// ---------------- causal flash attention (pair-balanced) ----------------
// Block = (pair p, hb). Low q-tile qtL=p, high q-tile qtH=31-p (64 rows each).
// Low tile's K-range [0..qtL] is a prefix of high's [0..qtH]: one staging pass
// feeds both. Every block does exactly 33 tile-computations.

__device__ __forceinline__ void proc_tile(
    const short8 aq[2], const char* Ks, const char* Vs, char* Psw,
    int lane, int w, bool diag, float* m, float* l, f32x4* o) {
  f32x4 sacc[4] = {};
  __builtin_amdgcn_s_setprio(1);
#pragma unroll
  for (int ct = 0; ct < 4; ++ct) {
    int row = ct * 16 + (lane & 15);
#pragma unroll
    for (int ks = 0; ks < 2; ++ks) {
      short8 bk = *(const short8*)(Ks + row * 128 +
                  ((ks * 64 + (lane >> 4) * 16) ^ ((row & 7) << 4)));
      sacc[ct] = __builtin_amdgcn_mfma_f32_16x16x32_bf16(aq[ks], bk, sacc[ct], 0, 0, 0);
    }
  }
  __builtin_amdgcn_s_setprio(0);
#pragma unroll
  for (int r = 0; r < 4; ++r) {
    int qrow = w * 16 + (lane >> 4) * 4 + r;  // tile-local q row
    float mx = -__builtin_inff();
#pragma unroll
    for (int ct = 0; ct < 4; ++ct) {
      float v = sacc[ct][r];  // already in log2 units (scale folded into Q)
      if (diag && (ct * 16 + (lane & 15)) > qrow) v = -__builtin_inff();
      sacc[ct][r] = v;
      mx = fmaxf(mx, v);
    }
#pragma unroll
    for (int dd = 1; dd < 16; dd <<= 1) mx = fmaxf(mx, __shfl_xor(mx, dd));
    float nm = fmaxf(m[r], mx);
    float al = exp2fast(m[r] - nm);
    m[r] = nm;
    float ps = 0.f;
#pragma unroll
    for (int ct = 0; ct < 4; ++ct) {
      float pp = exp2fast(sacc[ct][r] - nm);
      sacc[ct][r] = pp;
      ps += pp;
    }
#pragma unroll
    for (int dd = 1; dd < 16; dd <<= 1) ps += __shfl_xor(ps, dd);
    l[r] = l[r] * al + ps;
#pragma unroll
    for (int ct = 0; ct < 4; ++ct) o[ct][r] *= al;
  }
  // wave-private P -> LDS (swizzled), read back as A-fragments
#pragma unroll
  for (int ct = 0; ct < 4; ++ct)
#pragma unroll
    for (int r = 0; r < 4; ++r) {
      int row = (lane >> 4) * 4 + r;
      int cb = 2 * (ct * 16 + (lane & 15));
      *(unsigned short*)(Psw + row * 128 + (cb ^ ((row & 7) << 4))) = f2b(sacc[ct][r]);
    }
  __builtin_amdgcn_wave_barrier();
  short8 pa[2];
  {
    int row = lane & 15;
#pragma unroll
    for (int ks = 0; ks < 2; ++ks)
      pa[ks] = *(const short8*)(Psw + row * 128 +
               ((ks * 64 + (lane >> 4) * 16) ^ ((row & 7) << 4)));
  }
  __builtin_amdgcn_s_setprio(1);
#pragma unroll
  for (int ct = 0; ct < 4; ++ct) {
    int row = ct * 16 + (lane & 15);
#pragma unroll
    for (int ks = 0; ks < 2; ++ks) {
      short8 bv = *(const short8*)(Vs + row * 128 +
                  ((ks * 64 + (lane >> 4) * 16) ^ ((row & 7) << 4)));
      o[ct] = __builtin_amdgcn_mfma_f32_16x16x32_bf16(pa[ks], bv, o[ct], 0, 0, 0);
    }
  }
  __builtin_amdgcn_s_setprio(0);
}

__global__ __launch_bounds__(256) void attn_kernel(
    const unsigned short* __restrict__ Qb, const unsigned short* __restrict__ Kb,
    const unsigned short* __restrict__ VTb, unsigned short* __restrict__ Ob) {
  __shared__ unsigned short Ks[64 * 64];
  __shared__ unsigned short Vs[64 * 64];
  __shared__ unsigned short Ps[4 * 16 * 64];
  const int tid = threadIdx.x, w = tid >> 6, lane = tid & 63;
  const int p = blockIdx.x, hb = blockIdx.y;
  const int qtL = p, qtH = 31 - p;
  const int h = hb >> 1, b = hb & 1;
  const unsigned short* Qhb = Qb + (size_t)hb * 2048 * 64;
  const unsigned short* Khb = Kb + (size_t)hb * 2048 * 64;
  const unsigned short* Vhb = VTb + (size_t)hb * 64 * 2048;
  char* Psw = (char*)Ps + w * 2048;

  short8 aqL[2], aqH[2];
  {
    int rowL = qtL * 64 + w * 16 + (lane & 15);
    int rowH = qtH * 64 + w * 16 + (lane & 15);
#pragma unroll
    for (int ks = 0; ks < 2; ++ks) {
      aqL[ks] = *(const short8*)(Qhb + (size_t)rowL * 64 + ks * 32 + (lane >> 4) * 8);
      aqH[ks] = *(const short8*)(Qhb + (size_t)rowH * 64 + ks * 32 + (lane >> 4) * 8);
    }
  }
  float mL[4], lL[4], mH[4], lH[4];
#pragma unroll
  for (int r = 0; r < 4; ++r) {
    mL[r] = -__builtin_inff(); lL[r] = 0.f;
    mH[r] = -__builtin_inff(); lH[r] = 0.f;
  }
  f32x4 oL[4] = {}, oH[4] = {};

  // staging geometry: 512 chunks of 16B per 8KB tile; this thread owns chunks tid, tid+256
  const int r0 = tid >> 3, f0 = tid & 7;           // rows r0 and r0+32, same column
  const int so0 = r0 * 128 + ((f0 * 16) ^ ((r0 & 7) << 4));
  short8 gK[2], gV[2];
  {  // prologue: load tile kt=0 into regs
    gK[0] = *(const short8*)(Khb + (size_t)r0 * 64 + f0 * 8);
    gK[1] = *(const short8*)(Khb + (size_t)(r0 + 32) * 64 + f0 * 8);
    gV[0] = *(const short8*)(Vhb + (size_t)r0 * 2048 + f0 * 8);
    gV[1] = *(const short8*)(Vhb + (size_t)(r0 + 32) * 2048 + f0 * 8);
  }

  for (int kt = 0; kt <= qtH; ++kt) {
    *(short8*)((char*)Ks + so0) = gK[0];
    *(short8*)((char*)Ks + so0 + 32 * 128) = gK[1];
    *(short8*)((char*)Vs + so0) = gV[0];
    *(short8*)((char*)Vs + so0 + 32 * 128) = gV[1];
    __syncthreads();
    if (kt < qtH) {  // async-issue next tile's loads; latency hides under compute
      int kk0 = (kt + 1) * 64;
      gK[0] = *(const short8*)(Khb + (size_t)(kk0 + r0) * 64 + f0 * 8);
      gK[1] = *(const short8*)(Khb + (size_t)(kk0 + r0 + 32) * 64 + f0 * 8);
      gV[0] = *(const short8*)(Vhb + (size_t)r0 * 2048 + kk0 + f0 * 8);
      gV[1] = *(const short8*)(Vhb + (size_t)(r0 + 32) * 2048 + kk0 + f0 * 8);
    }
    proc_tile(aqH, (const char*)Ks, (const char*)Vs, Psw, lane, w,
              kt == qtH, mH, lH, oH);
    if (kt <= qtL)
      proc_tile(aqL, (const char*)Ks, (const char*)Vs, Psw, lane, w,
                kt == qtL, mL, lL, oL);
    __syncthreads();
  }

  float invL[4], invH[4];
#pragma unroll
  for (int r = 0; r < 4; ++r) { invL[r] = 1.0f / lL[r]; invH[r] = 1.0f / lH[r]; }
#pragma unroll
  for (int ct = 0; ct < 4; ++ct) {
    int col = h * 64 + ct * 16 + (lane & 15);
#pragma unroll
    for (int r = 0; r < 4; ++r) {
      int sL = qtL * 64 + w * 16 + (lane >> 4) * 4 + r;
      int sH = qtH * 64 + w * 16 + (lane >> 4) * 4 + r;
      Ob[(size_t)(b * 2048 + sL) * 1024 + col] = f2b(oL[ct][r] * invL[r]);
      Ob[(size_t)(b * 2048 + sH) * 1024 + col] = f2b(oH[ct][r] * invH[r]);
    }
  }
}

// ---------------- launch ----------------

extern "C" void kernel_launch(void* const* d_in, const int* in_sizes, int n_in,
                              void* d_out, int out_size, void* d_ws, size_t ws_size,
                              hipStream_t stream) {
  const float* x  = (const float*)d_in[0];
  const float* wq = (const float*)d_in[1];
  const float* wk = (const float*)d_in[2];
  const float* wv = (const float*)d_in[3];
  const float* wo = (const float*)d_in[4];
  float* out = (float*)d_out;

  char* ws = (char*)d_ws;
  const size_t SZ = 8388608;  // 8 MiB
  unsigned short* xb  = (unsigned short*)(ws);
  unsigned short* wT  = (unsigned short*)(ws + SZ);       // 4 x 2MiB (q,k,v,o)
  unsigned short* Qb  = (unsigned short*)(ws + 2 * SZ);
  unsigned short* Kb  = (unsigned short*)(ws + 3 * SZ);
  unsigned short* VTb = (unsigned short*)(ws + 4 * SZ);
  unsigned short* Ob  = (unsigned short*)(ws + 5 * SZ);
  float* ctab = (float*)(ws + 6 * SZ);
  float* stab = (float*)(ws + 6 * SZ + 262144);
  if (ws_size < 6 * SZ + 2 * 262144) return;  // ws too small: fail loudly (zeros)

  cast_x_kernel<<<4096, 256, 0, stream>>>(x, xb);
  transpose_cast_kernel<<<dim3(32, 32, 4), 256, 0, stream>>>(wq, wk, wv, wo, wT);
  rope_tab_kernel<<<256, 256, 0, stream>>>(ctab, stab);
  gemm_kernel<<<dim3(32, 8, 3), 256, 0, stream>>>(xb, wT, Qb, Kb, VTb, nullptr, ctab, stab, 0);
  attn_kernel<<<dim3(16, 32), 256, 0, stream>>>(Qb, Kb, VTb, Ob);
  gemm_kernel<<<dim3(32, 8, 1), 256, 0, stream>>>(Ob, wT + 3 * 1048576, Qb, Kb, VTb, out,
                                                  ctab, stab, 1);
}